// Round 2
// baseline (716.538 us; speedup 1.0000x reference)
//
#include <hip/hip_runtime.h>
#include <hip/hip_bf16.h>
#include <math.h>

// Problem constants (B=1)
#define S_LEN   2048
#define DMODEL  1024
#define NH      16
#define DH      64
#define WIN     256

// ---------------------------------------------------------------------------
// fp32 GEMM body: C[M=2048][N=1024] = A[2048][1024] @ W[1024][1024] + bias
// BM=64, BN=128, BK=16, 256 threads, 4x8 register tile per thread.
// ---------------------------------------------------------------------------
__device__ __forceinline__ void gemm_body(const float* __restrict__ A,
                                          const float* __restrict__ W,
                                          const float* __restrict__ bias,
                                          float* __restrict__ C) {
    constexpr int GM = S_LEN, GN = DMODEL, GK = DMODEL;
    (void)GM;
    constexpr int BM = 64, BN = 128, BK = 16;
    constexpr int AP = BM + 4;   // 68: transposed-A pitch (float4-aligned, bank-spread)
    constexpr int BP = BN + 4;   // 132
    __shared__ float As[BK][AP];   // As[k][m]
    __shared__ float Bs[BK][BP];   // Bs[k][n]

    const int tid  = threadIdx.x;
    const int tx   = tid & 15;     // col group: cols tx*8 .. tx*8+7
    const int ty   = tid >> 4;     // row group: rows ty*4 .. ty*4+3
    const int brow = blockIdx.y * BM;
    const int bcol = blockIdx.x * BN;

    float acc[4][8];
#pragma unroll
    for (int i = 0; i < 4; ++i)
#pragma unroll
        for (int j = 0; j < 8; ++j) acc[i][j] = 0.f;

    // staging indices
    const int ar  = tid >> 2;          // 0..63   A row
    const int ak4 = (tid & 3) << 2;    // 0..12   A k-quad
    const int bk0 = tid >> 5;          // 0..7    B row (and +8)
    const int bc4 = (tid & 31) << 2;   // 0..124  B col quad

    for (int k0 = 0; k0 < GK; k0 += BK) {
        __syncthreads();
        // stage A (transposed into LDS)
        float4 a4 = *(const float4*)&A[(brow + ar) * GK + k0 + ak4];
        As[ak4 + 0][ar] = a4.x;
        As[ak4 + 1][ar] = a4.y;
        As[ak4 + 2][ar] = a4.z;
        As[ak4 + 3][ar] = a4.w;
        // stage B (row-major)
        float4 b4 = *(const float4*)&W[(k0 + bk0) * GN + bcol + bc4];
        *(float4*)&Bs[bk0][bc4] = b4;
        float4 b5 = *(const float4*)&W[(k0 + bk0 + 8) * GN + bcol + bc4];
        *(float4*)&Bs[bk0 + 8][bc4] = b5;
        __syncthreads();

#pragma unroll
        for (int k = 0; k < BK; ++k) {
            float4 av  = *(const float4*)&As[k][ty * 4];
            float4 bva = *(const float4*)&Bs[k][tx * 8];
            float4 bvb = *(const float4*)&Bs[k][tx * 8 + 4];
            float aa[4] = {av.x, av.y, av.z, av.w};
            float bb[8] = {bva.x, bva.y, bva.z, bva.w, bvb.x, bvb.y, bvb.z, bvb.w};
#pragma unroll
            for (int i = 0; i < 4; ++i)
#pragma unroll
                for (int j = 0; j < 8; ++j)
                    acc[i][j] = fmaf(aa[i], bb[j], acc[i][j]);
        }
    }

    // epilogue: +bias, write
    const int ccol = bcol + tx * 8;
    float4 ba = *(const float4*)&bias[ccol];
    float4 bb2 = *(const float4*)&bias[ccol + 4];
#pragma unroll
    for (int i = 0; i < 4; ++i) {
        int row = brow + ty * 4 + i;
        float4 o1, o2;
        o1.x = acc[i][0] + ba.x;  o1.y = acc[i][1] + ba.y;
        o1.z = acc[i][2] + ba.z;  o1.w = acc[i][3] + ba.w;
        o2.x = acc[i][4] + bb2.x; o2.y = acc[i][5] + bb2.y;
        o2.z = acc[i][6] + bb2.z; o2.w = acc[i][7] + bb2.w;
        *(float4*)&C[row * GN + ccol]     = o1;
        *(float4*)&C[row * GN + ccol + 4] = o2;
    }
}

// Fused QKV: gridDim.z picks (Wq,bq,Q) / (Wk,bk,K) / (Wv,bv,V)
__global__ __launch_bounds__(256) void qkv_kernel(
        const float* __restrict__ x,
        const float* __restrict__ Wq, const float* __restrict__ bq, float* __restrict__ Q,
        const float* __restrict__ Wk, const float* __restrict__ bk, float* __restrict__ K,
        const float* __restrict__ Wv, const float* __restrict__ bv, float* __restrict__ V) {
    const float* W; const float* b; float* C;
    if (blockIdx.z == 0)      { W = Wq; b = bq; C = Q; }
    else if (blockIdx.z == 1) { W = Wk; b = bk; C = K; }
    else                      { W = Wv; b = bv; C = V; }
    gemm_body(x, W, b, C);
}

__global__ __launch_bounds__(256) void oproj_kernel(
        const float* __restrict__ A, const float* __restrict__ W,
        const float* __restrict__ b, float* __restrict__ C) {
    gemm_body(A, W, b, C);
}

// ---------------------------------------------------------------------------
// Banded flash attention, fp32.
// Block = (64-row Q tile, head). 256 threads, 4x4 score tile per thread.
// LDS: Q^T, K^T (for conflict-light S-compute), V row-major, P^T.
// ---------------------------------------------------------------------------
__global__ __launch_bounds__(256) void attn_kernel(
        const float* __restrict__ Q, const float* __restrict__ K,
        const float* __restrict__ V, float* __restrict__ O) {
    constexpr int QB = 64, KB = 64;
    constexpr int P = 68;                 // LDS pitch (floats): float4-aligned, bank-spread
    __shared__ float Qst[DH][P];          // [k][row]  (pre-scaled)
    __shared__ float Kst[DH][P];          // [k][col]
    __shared__ float Vs [KB][P];          // [col][dh]
    __shared__ float Pst[KB][P];          // [col][row]

    const int tid = threadIdx.x;
    const int tx  = tid & 15;             // score-col group / dh group
    const int ty  = tid >> 4;             // score-row group
    const int i0  = blockIdx.x * QB;
    const int h   = blockIdx.y;
    const float scale = 0.125f;           // 1/sqrt(64)

    // stage Q transposed + scaled (once)
#pragma unroll
    for (int rep = 0; rep < 4; ++rep) {
        int flat = tid + rep * 256;       // 0..1023
        int row  = flat >> 4;             // 0..63
        int k4   = (flat & 15) << 2;      // 0..60
        float4 q = *(const float4*)&Q[(i0 + row) * DMODEL + h * DH + k4];
        Qst[k4 + 0][row] = q.x * scale;
        Qst[k4 + 1][row] = q.y * scale;
        Qst[k4 + 2][row] = q.z * scale;
        Qst[k4 + 3][row] = q.w * scale;
    }

    float m[4], l[4], o[4][4];
#pragma unroll
    for (int i = 0; i < 4; ++i) {
        m[i] = -INFINITY; l[i] = 0.f;
#pragma unroll
        for (int j = 0; j < 4; ++j) o[i][j] = 0.f;
    }

    // tile range: band tiles first (keeps running max finite), global tile 0 last
    int t_lo, t_hi;
    if (i0 == 0) { t_lo = 0; t_hi = S_LEN / KB - 1; }   // row 0 is global: all tiles
    else {
        int lo = i0 - WIN;           if (lo < 0) lo = 0;
        int hi = i0 + QB - 1 + WIN;  if (hi > S_LEN - 1) hi = S_LEN - 1;
        t_lo = lo / KB; t_hi = hi / KB;
    }
    const int nband = t_hi - t_lo + 1;
    const int nt    = nband + (t_lo > 0 ? 1 : 0);

    for (int it = 0; it < nt; ++it) {
        const int t  = (it < nband) ? (t_lo + it) : 0;
        const int j0 = t * KB;

        __syncthreads();   // prior-tile LDS reads done before overwrite
        // stage K transposed + V row-major
#pragma unroll
        for (int rep = 0; rep < 4; ++rep) {
            int flat = tid + rep * 256;
            int row  = flat >> 4;
            int k4   = (flat & 15) << 2;
            float4 kk = *(const float4*)&K[(j0 + row) * DMODEL + h * DH + k4];
            Kst[k4 + 0][row] = kk.x;
            Kst[k4 + 1][row] = kk.y;
            Kst[k4 + 2][row] = kk.z;
            Kst[k4 + 3][row] = kk.w;
            float4 vv = *(const float4*)&V[(j0 + row) * DMODEL + h * DH + k4];
            *(float4*)&Vs[row][k4] = vv;
        }
        __syncthreads();

        // S = (Q*scale) K^T  : 4x4 per thread
        float s[4][4];
#pragma unroll
        for (int i = 0; i < 4; ++i)
#pragma unroll
            for (int j = 0; j < 4; ++j) s[i][j] = 0.f;
#pragma unroll
        for (int k = 0; k < DH; ++k) {
            float4 qv = *(const float4*)&Qst[k][ty * 4];
            float4 kv = *(const float4*)&Kst[k][tx * 4];
            float qa[4] = {qv.x, qv.y, qv.z, qv.w};
            float kb[4] = {kv.x, kv.y, kv.z, kv.w};
#pragma unroll
            for (int i = 0; i < 4; ++i)
#pragma unroll
                for (int j = 0; j < 4; ++j)
                    s[i][j] = fmaf(qa[i], kb[j], s[i][j]);
        }

        // mask: allowed iff |r-c|<=WIN or r==0 or c==0
#pragma unroll
        for (int i = 0; i < 4; ++i) {
            int r = i0 + ty * 4 + i;
#pragma unroll
            for (int j = 0; j < 4; ++j) {
                int c = j0 + tx * 4 + j;
                int d = r - c;
                bool ok = (d <= WIN && d >= -WIN) || (r == 0) || (c == 0);
                if (!ok) s[i][j] = -INFINITY;
            }
        }

        // online softmax per row (row spread over 16 lanes)
#pragma unroll
        for (int i = 0; i < 4; ++i) {
            float tm = fmaxf(fmaxf(s[i][0], s[i][1]), fmaxf(s[i][2], s[i][3]));
#pragma unroll
            for (int off = 1; off < 16; off <<= 1)
                tm = fmaxf(tm, __shfl_xor(tm, off, 64));
            float mn    = fmaxf(m[i], tm);
            float alpha = __expf(m[i] - mn);    // exp(-inf)=0 on first tile
            float ps = 0.f;
#pragma unroll
            for (int j = 0; j < 4; ++j) {
                s[i][j] = __expf(s[i][j] - mn); // masked: exp(-inf)=0
                ps += s[i][j];
            }
#pragma unroll
            for (int off = 1; off < 16; off <<= 1)
                ps += __shfl_xor(ps, off, 64);
            l[i] = l[i] * alpha + ps;
            m[i] = mn;
#pragma unroll
            for (int j = 0; j < 4; ++j) o[i][j] *= alpha;
            // write P transposed for the PV GEMM
#pragma unroll
            for (int j = 0; j < 4; ++j)
                Pst[tx * 4 + j][ty * 4 + i] = s[i][j];
        }
        __syncthreads();

        // O += P V : o[i][j] += sum_t P^T[t][row] * V[t][dh]
#pragma unroll
        for (int t2 = 0; t2 < KB; ++t2) {
            float4 pv = *(const float4*)&Pst[t2][ty * 4];
            float4 vv = *(const float4*)&Vs [t2][tx * 4];
            float pa[4] = {pv.x, pv.y, pv.z, pv.w};
            float vb[4] = {vv.x, vv.y, vv.z, vv.w};
#pragma unroll
            for (int i = 0; i < 4; ++i)
#pragma unroll
                for (int j = 0; j < 4; ++j)
                    o[i][j] = fmaf(pa[i], vb[j], o[i][j]);
        }
    }

    // epilogue: divide by l, write O[row][h*64 + dh]
#pragma unroll
    for (int i = 0; i < 4; ++i) {
        float inv = 1.f / l[i];
        float4 out;
        out.x = o[i][0] * inv; out.y = o[i][1] * inv;
        out.z = o[i][2] * inv; out.w = o[i][3] * inv;
        *(float4*)&O[(i0 + ty * 4 + i) * DMODEL + h * DH + tx * 4] = out;
    }
}

// ---------------------------------------------------------------------------
extern "C" void kernel_launch(void* const* d_in, const int* in_sizes, int n_in,
                              void* d_out, int out_size, void* d_ws, size_t ws_size,
                              hipStream_t stream) {
    const float* x  = (const float*)d_in[0];
    const float* Wq = (const float*)d_in[1];
    const float* bq = (const float*)d_in[2];
    const float* Wk = (const float*)d_in[3];
    const float* bk = (const float*)d_in[4];
    const float* Wv = (const float*)d_in[5];
    const float* bv = (const float*)d_in[6];
    const float* Wo = (const float*)d_in[7];
    const float* bo = (const float*)d_in[8];
    float* out = (float*)d_out;

    float* ws = (float*)d_ws;
    const int MAT = S_LEN * DMODEL;   // 2 M elements = 8 MB
    float* Qp = ws;
    float* Kp = ws + MAT;
    float* Vp = ws + 2 * MAT;
    float* Op = ws + 3 * MAT;

    // QKV projections (fused over gridDim.z)
    dim3 g1(DMODEL / 128, S_LEN / 64, 3);
    qkv_kernel<<<g1, 256, 0, stream>>>(x, Wq, bq, Qp, Wk, bk, Kp, Wv, bv, Vp);

    // banded attention
    dim3 g2(S_LEN / 64, NH, 1);
    attn_kernel<<<g2, 256, 0, stream>>>(Qp, Kp, Vp, Op);

    // output projection
    dim3 g3(DMODEL / 128, S_LEN / 64, 1);
    oproj_kernel<<<g3, 256, 0, stream>>>(Op, Wo, bo, out);
}

// Round 4
// 245.688 us; speedup vs baseline: 2.9165x; 2.9165x over previous
//
#include <hip/hip_runtime.h>
#include <hip/hip_bf16.h>
#include <math.h>

// Problem constants (B=1)
#define S_LEN   2048
#define DM      1024
#define NH      16
#define DH      64
#define WIN     256

typedef __attribute__((ext_vector_type(8))) short          bf16x8;
typedef __attribute__((ext_vector_type(4))) float          f32x4;
typedef __attribute__((ext_vector_type(8))) unsigned short u16x8;
typedef __attribute__((ext_vector_type(4))) unsigned short u16x4;
typedef unsigned short u16;

// fp32 -> bf16 round-to-nearest-even (finite inputs only)
__device__ __forceinline__ u16 f2bf(float f) {
    union { float f; unsigned u; } v; v.f = f;
    unsigned r = v.u + 0x7FFF + ((v.u >> 16) & 1);
    return (u16)(r >> 16);
}

// ---------------------------------------------------------------------------
// Pre-pass 1: x fp32 -> bf16 (row-major [2048][1024])
// ---------------------------------------------------------------------------
__global__ __launch_bounds__(256) void cvt_x_kernel(const float* __restrict__ x,
                                                    u16* __restrict__ xb) {
    int i = (blockIdx.x * 256 + threadIdx.x) * 8;
    float4 a = *(const float4*)&x[i];
    float4 b = *(const float4*)&x[i + 4];
    u16x8 o;
    o[0] = f2bf(a.x); o[1] = f2bf(a.y); o[2] = f2bf(a.z); o[3] = f2bf(a.w);
    o[4] = f2bf(b.x); o[5] = f2bf(b.y); o[6] = f2bf(b.z); o[7] = f2bf(b.w);
    *(u16x8*)&xb[i] = o;
}

// ---------------------------------------------------------------------------
// Pre-pass 2: W fp32 [K=in][N=out] -> Wt bf16 [N][K]  (z picks Wq/Wk/Wv/Wo)
// 64x64 tiles through LDS; both global sides coalesced.
// ---------------------------------------------------------------------------
__global__ __launch_bounds__(256) void cvt_wT_kernel(const float* __restrict__ Wq,
                                                     const float* __restrict__ Wk,
                                                     const float* __restrict__ Wv,
                                                     const float* __restrict__ Wo,
                                                     u16* __restrict__ WT) {
    __shared__ float Ws[64][65];
    const float* W = (blockIdx.z == 0) ? Wq : (blockIdx.z == 1) ? Wk
                   : (blockIdx.z == 2) ? Wv : Wo;
    u16* dst = WT + (size_t)blockIdx.z * (1u << 20);
    const int k0 = blockIdx.x * 64, n0 = blockIdx.y * 64;
    const int tid = threadIdx.x;
#pragma unroll
    for (int p = 0; p < 4; ++p) {
        int flat = tid + p * 256;
        int row = flat >> 4, c4 = (flat & 15) * 4;      // row = k index
        float4 v = *(const float4*)&W[(k0 + row) * DM + n0 + c4];
        Ws[row][c4 + 0] = v.x; Ws[row][c4 + 1] = v.y;
        Ws[row][c4 + 2] = v.z; Ws[row][c4 + 3] = v.w;
    }
    __syncthreads();
#pragma unroll
    for (int p = 0; p < 4; ++p) {
        int flat = tid + p * 256;
        int n = flat >> 4, k4 = (flat & 15) * 4;
        u16x4 o;
#pragma unroll
        for (int j = 0; j < 4; ++j) o[j] = f2bf(Ws[k4 + j][n]);
        *(u16x4*)&dst[(n0 + n) * DM + k0 + k4] = o;
    }
}

// ---------------------------------------------------------------------------
// bf16 MFMA GEMM: C[2048][1024] = A[2048][1024] @ Bt^T + bias
//   A   bf16 [M][K] row-major (k-contiguous)  -> MFMA A-operand
//   Bt  bf16 [N][K] row-major (k-contiguous)  -> MFMA B-operand
// 128x128 tile, BK=64, 4 waves (2x2, 64x64 each), acc 4x4 frags of 16x16x32.
// LDS tiles XOR-chunk-swizzled: elem ofs = row*64 + ((chunk^(row&7))*8),
// which makes both the staggered frag reads and staging writes conflict-free.
// ---------------------------------------------------------------------------
template<bool OBF>
__device__ __forceinline__ void gemm_mfma_body(const u16* __restrict__ A,
                                               const u16* __restrict__ Bt,
                                               const float* __restrict__ bias,
                                               u16* __restrict__ Cb,
                                               float* __restrict__ Cf) {
    __shared__ __align__(16) u16 As[128 * 64];
    __shared__ __align__(16) u16 Bs[128 * 64];
    const int tid = threadIdx.x;
    const int l = tid & 63, w = tid >> 6;
    const int wm = w >> 1, wn = w & 1;
    const int l15 = l & 15, lh = l >> 4;
    const int brow = blockIdx.y * 128, bcol = blockIdx.x * 128;

    f32x4 acc[4][4];
#pragma unroll
    for (int i = 0; i < 4; ++i)
#pragma unroll
        for (int j = 0; j < 4; ++j) acc[i][j] = (f32x4)0.f;

    const int srow = tid >> 3, sch = tid & 7;   // staging: 32 rows/pass, 8x16B chunks/row

    for (int k0 = 0; k0 < DM; k0 += 64) {
        __syncthreads();
#pragma unroll
        for (int p = 0; p < 4; ++p) {
            int row = srow + p * 32;
            int lofs = row * 64 + ((sch ^ (row & 7)) * 8);
            *(bf16x8*)&As[lofs] = *(const bf16x8*)&A [(brow + row) * DM + k0 + sch * 8];
            *(bf16x8*)&Bs[lofs] = *(const bf16x8*)&Bt[(bcol + row) * DM + k0 + sch * 8];
        }
        __syncthreads();
#pragma unroll
        for (int ks = 0; ks < 2; ++ks) {
            bf16x8 af[4], bf[4];
#pragma unroll
            for (int i = 0; i < 4; ++i) {
                int ra = wm * 64 + i * 16 + l15;
                af[i] = *(const bf16x8*)&As[ra * 64 + (((ks * 4 + lh) ^ (ra & 7)) * 8)];
                int rb = wn * 64 + i * 16 + l15;
                bf[i] = *(const bf16x8*)&Bs[rb * 64 + (((ks * 4 + lh) ^ (rb & 7)) * 8)];
            }
#pragma unroll
            for (int i = 0; i < 4; ++i)
#pragma unroll
                for (int j = 0; j < 4; ++j)
                    acc[i][j] = __builtin_amdgcn_mfma_f32_16x16x32_bf16(af[i], bf[j], acc[i][j], 0, 0, 0);
        }
    }
    // epilogue: D frag layout row=(lh)*4+rr, col=l15
#pragma unroll
    for (int j = 0; j < 4; ++j) {
        int gcol = bcol + wn * 64 + j * 16 + l15;
        float bz = bias[gcol];
#pragma unroll
        for (int i = 0; i < 4; ++i) {
            int grow = brow + wm * 64 + i * 16 + lh * 4;
#pragma unroll
            for (int rr = 0; rr < 4; ++rr) {
                float v = acc[i][j][rr] + bz;
                if (OBF) Cb[(grow + rr) * DM + gcol] = f2bf(v);
                else     Cf[(grow + rr) * DM + gcol] = v;
            }
        }
    }
}

__global__ __launch_bounds__(256) void qkv_mfma_kernel(
        const u16* __restrict__ xb,
        const u16* __restrict__ WqT, const float* __restrict__ bq, u16* __restrict__ Qb,
        const u16* __restrict__ WkT, const float* __restrict__ bk, u16* __restrict__ Kb,
        const u16* __restrict__ WvT, const float* __restrict__ bv, u16* __restrict__ Vb) {
    const u16* Wt; const float* b; u16* C;
    if (blockIdx.z == 0)      { Wt = WqT; b = bq; C = Qb; }
    else if (blockIdx.z == 1) { Wt = WkT; b = bk; C = Kb; }
    else                      { Wt = WvT; b = bv; C = Vb; }
    gemm_mfma_body<true>(xb, Wt, b, C, nullptr);
}

__global__ __launch_bounds__(256) void oproj_mfma_kernel(
        const u16* __restrict__ Ob, const u16* __restrict__ WoT,
        const float* __restrict__ bo, float* __restrict__ out) {
    gemm_mfma_body<false>(Ob, WoT, bo, nullptr, out);
}

// ---------------------------------------------------------------------------
// Pre-pass 3: V bf16 [token][1024] -> VT bf16 [h][dh][token]  (PV B-operand
// wants kv-contiguous [dh][kv]). Global-gather transpose; tiles are L1/L2 hot.
// ---------------------------------------------------------------------------
__global__ __launch_bounds__(256) void vT_kernel(const u16* __restrict__ Vb,
                                                 u16* __restrict__ VT) {
    const int j0 = blockIdx.x * 64, h = blockIdx.y;
    const int tid = threadIdx.x;
#pragma unroll
    for (int p = 0; p < 2; ++p) {
        int flat = tid + p * 256;
        int dh = flat >> 3, tc = flat & 7;
        u16x8 o;
#pragma unroll
        for (int t = 0; t < 8; ++t)
            o[t] = Vb[(j0 + tc * 8 + t) * DM + h * DH + dh];
        *(u16x8*)&VT[(h * DH + dh) * S_LEN + j0 + tc * 8] = o;
    }
}

// ---------------------------------------------------------------------------
// MFMA flash attention (banded + global token 0).
// Block = (64 Q rows, head), 4 independent waves of 16 Q rows. NO barriers.
// Q frags preloaded to regs; K / VT frags read direct from global (L1/L2-hot);
// P routes through wave-private LDS (pitch 72 u16 to spread banks).
// ---------------------------------------------------------------------------
__global__ __launch_bounds__(256) void attn_mfma_kernel(const u16* __restrict__ Qb,
                                                        const u16* __restrict__ Kb,
                                                        const u16* __restrict__ VT,
                                                        u16* __restrict__ Ob) {
    __shared__ __align__(16) u16 Pl[4 * 16 * 72];
    const int tid = threadIdx.x;
    const int w = tid >> 6, l = tid & 63;
    const int l15 = l & 15, lh = l >> 4;
    const int i0 = blockIdx.x * 64, h = blockIdx.y;
    const int q0 = i0 + w * 16;
    u16* Pw = &Pl[w * 16 * 72];

    // Q A-frags (A[m=qrow][k=dh]): lane row l15, k-chunk lh*8, ks in {0,1}
    bf16x8 qf[2];
    {
        int qr = q0 + l15;
        qf[0] = *(const bf16x8*)&Qb[qr * DM + h * DH + lh * 8];
        qf[1] = *(const bf16x8*)&Qb[qr * DM + h * DH + 32 + lh * 8];
    }

    f32x4 o[4];
    float m[4], lsum[4];
#pragma unroll
    for (int fc = 0; fc < 4; ++fc) o[fc] = (f32x4)0.f;
#pragma unroll
    for (int rr = 0; rr < 4; ++rr) { m[rr] = -INFINITY; lsum[rr] = 0.f; }

    // per-wave tile list: band (ascending), then global tile 0 if not in band.
    int t_lo, t_hi;
    if (q0 == 0) { t_lo = 0; t_hi = S_LEN / 64 - 1; }
    else {
        int lo = q0 - WIN;      if (lo < 0) lo = 0;
        int hi = q0 + 15 + WIN; if (hi > S_LEN - 1) hi = S_LEN - 1;
        t_lo = lo >> 6; t_hi = hi >> 6;
    }
    const int nband = t_hi - t_lo + 1;
    const int nt = nband + (t_lo > 0 ? 1 : 0);

    for (int it = 0; it < nt; ++it) {
        const int j0 = ((it < nband) ? (t_lo + it) : 0) << 6;

        // S = Q K^T : B[k=dh][n=kv] read from Kb[kv][dh] (k-contiguous)
        f32x4 s[4];
#pragma unroll
        for (int fc = 0; fc < 4; ++fc) s[fc] = (f32x4)0.f;
#pragma unroll
        for (int ks = 0; ks < 2; ++ks)
#pragma unroll
            for (int fc = 0; fc < 4; ++fc) {
                bf16x8 kf = *(const bf16x8*)&Kb[(j0 + fc * 16 + l15) * DM + h * DH + ks * 32 + lh * 8];
                s[fc] = __builtin_amdgcn_mfma_f32_16x16x32_bf16(qf[ks], kf, s[fc], 0, 0, 0);
            }

        // scale + mask (D layout: row=lh*4+rr, col=fc*16+l15)
#pragma unroll
        for (int fc = 0; fc < 4; ++fc)
#pragma unroll
            for (int rr = 0; rr < 4; ++rr) {
                float sv = s[fc][rr] * 0.125f;
                int r = q0 + lh * 4 + rr;
                int c = j0 + fc * 16 + l15;
                int d = r - c;
                bool ok = (d <= WIN && -d <= WIN) || (r == 0) || (c == 0);
                s[fc][rr] = ok ? sv : -INFINITY;
            }

        // online softmax: 4 rows/lane, row spread over 16 lanes (same lh group)
#pragma unroll
        for (int rr = 0; rr < 4; ++rr) {
            float tm = fmaxf(fmaxf(s[0][rr], s[1][rr]), fmaxf(s[2][rr], s[3][rr]));
#pragma unroll
            for (int mk = 1; mk < 16; mk <<= 1) tm = fmaxf(tm, __shfl_xor(tm, mk, 64));
            float mn = fmaxf(m[rr], tm);
            float alpha = __expf(m[rr] - mn);   // first tile: exp(-inf)=0
            m[rr] = mn;
            float sum = 0.f;
#pragma unroll
            for (int fc = 0; fc < 4; ++fc) {
                float p = __expf(s[fc][rr] - mn);
                s[fc][rr] = p;
                sum += p;
            }
#pragma unroll
            for (int mk = 1; mk < 16; mk <<= 1) sum += __shfl_xor(sum, mk, 64);
            lsum[rr] = lsum[rr] * alpha + sum;
#pragma unroll
            for (int fc = 0; fc < 4; ++fc) o[fc][rr] *= alpha;
        }

        // P -> wave-private LDS as bf16 [qrow16][kv64], pitch 72
#pragma unroll
        for (int fc = 0; fc < 4; ++fc)
#pragma unroll
            for (int rr = 0; rr < 4; ++rr)
                Pw[(lh * 4 + rr) * 72 + fc * 16 + l15] = f2bf(s[fc][rr]);
        asm volatile("s_waitcnt lgkmcnt(0)" ::: "memory");

        // O += P V : A=P[q][kv] from LDS, B[k=kv][n=dh] from VT[dh][kv]
#pragma unroll
        for (int ks = 0; ks < 2; ++ks) {
            bf16x8 pa = *(const bf16x8*)&Pw[l15 * 72 + ks * 32 + lh * 8];
#pragma unroll
            for (int fc = 0; fc < 4; ++fc) {
                bf16x8 vf = *(const bf16x8*)&VT[(h * DH + fc * 16 + l15) * S_LEN + j0 + ks * 32 + lh * 8];
                o[fc] = __builtin_amdgcn_mfma_f32_16x16x32_bf16(pa, vf, o[fc], 0, 0, 0);
            }
        }
    }

    // epilogue: /lsum, write bf16
#pragma unroll
    for (int rr = 0; rr < 4; ++rr) {
        float inv = 1.0f / lsum[rr];
#pragma unroll
        for (int fc = 0; fc < 4; ++fc)
            Ob[(q0 + lh * 4 + rr) * DM + h * DH + fc * 16 + l15] = f2bf(o[fc][rr] * inv);
    }
}

// ---------------------------------------------------------------------------
extern "C" void kernel_launch(void* const* d_in, const int* in_sizes, int n_in,
                              void* d_out, int out_size, void* d_ws, size_t ws_size,
                              hipStream_t stream) {
    const float* x  = (const float*)d_in[0];
    const float* Wq = (const float*)d_in[1];
    const float* bq = (const float*)d_in[2];
    const float* Wk = (const float*)d_in[3];
    const float* bk = (const float*)d_in[4];
    const float* Wv = (const float*)d_in[5];
    const float* bv = (const float*)d_in[6];
    const float* Wo = (const float*)d_in[7];
    const float* bo = (const float*)d_in[8];
    float* out = (float*)d_out;

    char* W = (char*)d_ws;
    u16* xb  = (u16*)(W);                        // 4 MB  (reused as Ob after qkv)
    u16* WT  = (u16*)(W + ((size_t)4  << 20));   // 4 x 2 MB = 8 MB
    u16* Qb  = (u16*)(W + ((size_t)12 << 20));   // 4 MB
    u16* Kb  = (u16*)(W + ((size_t)16 << 20));   // 4 MB
    u16* Vb  = (u16*)(W + ((size_t)20 << 20));   // 4 MB
    u16* VT  = (u16*)(W + ((size_t)24 << 20));   // 4 MB   (total 28 MB)
    u16* Ob  = xb;                               // x dead after qkv
    const u16* WqT = WT;
    const u16* WkT = WT + (1u << 20);
    const u16* WvT = WT + (2u << 20);
    const u16* WoT = WT + (3u << 20);

    cvt_x_kernel <<<dim3(S_LEN * DM / (256 * 8)), 256, 0, stream>>>(x, xb);
    cvt_wT_kernel<<<dim3(16, 16, 4), 256, 0, stream>>>(Wq, Wk, Wv, Wo, WT);
    qkv_mfma_kernel<<<dim3(8, 16, 3), 256, 0, stream>>>(xb, WqT, bq, Qb,
                                                        WkT, bk, Kb, WvT, bv, Vb);
    vT_kernel<<<dim3(32, 16), 256, 0, stream>>>(Vb, VT);
    attn_mfma_kernel<<<dim3(32, 16), 256, 0, stream>>>(Qb, Kb, VT, Ob);
    oproj_mfma_kernel<<<dim3(8, 16), 256, 0, stream>>>(Ob, WoT, bo, out);
}

// Round 5
// 174.317 us; speedup vs baseline: 4.1105x; 1.4094x over previous
//
#include <hip/hip_runtime.h>
#include <hip/hip_bf16.h>
#include <math.h>

// Problem constants (B=1)
#define S_LEN   2048
#define DM      1024
#define NH      16
#define DH      64
#define WIN     256

typedef __attribute__((ext_vector_type(8))) short          bf16x8;
typedef __attribute__((ext_vector_type(4))) float          f32x4;
typedef __attribute__((ext_vector_type(8))) unsigned short u16x8;
typedef __attribute__((ext_vector_type(4))) unsigned short u16x4;
typedef unsigned short u16;

// async global->LDS, 16B per lane, linear LDS dest (wave-uniform base + lane*16)
#define GLDS(gsrc, ldst)                                                        \
    __builtin_amdgcn_global_load_lds(                                           \
        (const __attribute__((address_space(1))) void*)(gsrc),                  \
        (__attribute__((address_space(3))) void*)(ldst), 16, 0, 0)

// fp32 -> bf16 round-to-nearest-even (finite inputs only)
__device__ __forceinline__ u16 f2bf(float f) {
    union { float f; unsigned u; } v; v.f = f;
    unsigned r = v.u + 0x7FFF + ((v.u >> 16) & 1);
    return (u16)(r >> 16);
}

// ---------------------------------------------------------------------------
// Pre-pass 1: x fp32 -> bf16 (row-major [2048][1024])
// ---------------------------------------------------------------------------
__global__ __launch_bounds__(256) void cvt_x_kernel(const float* __restrict__ x,
                                                    u16* __restrict__ xb) {
    int i = (blockIdx.x * 256 + threadIdx.x) * 8;
    float4 a = *(const float4*)&x[i];
    float4 b = *(const float4*)&x[i + 4];
    u16x8 o;
    o[0] = f2bf(a.x); o[1] = f2bf(a.y); o[2] = f2bf(a.z); o[3] = f2bf(a.w);
    o[4] = f2bf(b.x); o[5] = f2bf(b.y); o[6] = f2bf(b.z); o[7] = f2bf(b.w);
    *(u16x8*)&xb[i] = o;
}

// ---------------------------------------------------------------------------
// Pre-pass 2: W fp32 [K=in][N=out] -> Wt bf16 [N][K]  (z picks Wq/Wk/Wv/Wo)
// ---------------------------------------------------------------------------
__global__ __launch_bounds__(256) void cvt_wT_kernel(const float* __restrict__ Wq,
                                                     const float* __restrict__ Wk,
                                                     const float* __restrict__ Wv,
                                                     const float* __restrict__ Wo,
                                                     u16* __restrict__ WT) {
    __shared__ float Ws[64][65];
    const float* W = (blockIdx.z == 0) ? Wq : (blockIdx.z == 1) ? Wk
                   : (blockIdx.z == 2) ? Wv : Wo;
    u16* dst = WT + (size_t)blockIdx.z * (1u << 20);
    const int k0 = blockIdx.x * 64, n0 = blockIdx.y * 64;
    const int tid = threadIdx.x;
#pragma unroll
    for (int p = 0; p < 4; ++p) {
        int flat = tid + p * 256;
        int row = flat >> 4, c4 = (flat & 15) * 4;      // row = k index
        float4 v = *(const float4*)&W[(k0 + row) * DM + n0 + c4];
        Ws[row][c4 + 0] = v.x; Ws[row][c4 + 1] = v.y;
        Ws[row][c4 + 2] = v.z; Ws[row][c4 + 3] = v.w;
    }
    __syncthreads();
#pragma unroll
    for (int p = 0; p < 4; ++p) {
        int flat = tid + p * 256;
        int n = flat >> 4, k4 = (flat & 15) * 4;
        u16x4 o;
#pragma unroll
        for (int j = 0; j < 4; ++j) o[j] = f2bf(Ws[k4 + j][n]);
        *(u16x4*)&dst[(n0 + n) * DM + k0 + k4] = o;
    }
}

// ---------------------------------------------------------------------------
// bf16 MFMA GEMM: C[2048][1024] = A @ Bt^T + bias
// BM=64, BN=128, BK=64; 4 waves (2x2: 32x64 each); acc 2x4 frags 16x16x32.
// Staging via global_load_lds width=16: linear LDS dest, PRE-SWIZZLED global
// source (lane chunk g = (l&7)^(l>>3)); frag reads XOR-unswizzle -> <=2-way.
// ---------------------------------------------------------------------------
template<bool OBF>
__device__ __forceinline__ void gemm_mfma_body(const u16* __restrict__ A,
                                               const u16* __restrict__ Bt,
                                               const float* __restrict__ bias,
                                               u16* __restrict__ Cb,
                                               float* __restrict__ Cf) {
    __shared__ __align__(16) u16 As[64 * 64];    // 8 KB
    __shared__ __align__(16) u16 Bs[128 * 64];   // 16 KB
    const int tid = threadIdx.x;
    const int l = tid & 63, w = tid >> 6;
    const int wm = w >> 1, wn = w & 1;
    const int l15 = l & 15, lh = l >> 4;
    const int brow = blockIdx.y * 64, bcol = blockIdx.x * 128;

    f32x4 acc[2][4];
#pragma unroll
    for (int i = 0; i < 2; ++i)
#pragma unroll
        for (int j = 0; j < 4; ++j) acc[i][j] = (f32x4)0.f;

    // per-lane staging source (element offsets); row % 8 == lr always
    const int lr = l >> 3, lc = l & 7, g = lc ^ lr;
    const u16* aSrc = A  + (size_t)(brow + w * 16 + lr) * DM + g * 8;
    const u16* bSrc = Bt + (size_t)(bcol + w * 32 + lr) * DM + g * 8;

    for (int k0 = 0; k0 < DM; k0 += 64) {
        __syncthreads();
        // A: 2 insts/wave (rows w*16 .. +16), B: 4 insts/wave (rows w*32 .. +32)
#pragma unroll
        for (int i = 0; i < 2; ++i)
            GLDS(aSrc + i * 8 * DM + k0, &As[(w * 2 + i) * 512]);
#pragma unroll
        for (int i = 0; i < 4; ++i)
            GLDS(bSrc + i * 8 * DM + k0, &Bs[(w * 4 + i) * 512]);
        __syncthreads();   // compiler drains vmcnt before barrier

#pragma unroll
        for (int ks = 0; ks < 2; ++ks) {
            bf16x8 af[2], bf[4];
#pragma unroll
            for (int i = 0; i < 2; ++i) {
                int ra = wm * 32 + i * 16 + l15;
                af[i] = *(const bf16x8*)&As[ra * 64 + (((ks * 4 + lh) ^ (ra & 7)) * 8)];
            }
#pragma unroll
            for (int j = 0; j < 4; ++j) {
                int rb = wn * 64 + j * 16 + l15;
                bf[j] = *(const bf16x8*)&Bs[rb * 64 + (((ks * 4 + lh) ^ (rb & 7)) * 8)];
            }
#pragma unroll
            for (int i = 0; i < 2; ++i)
#pragma unroll
                for (int j = 0; j < 4; ++j)
                    acc[i][j] = __builtin_amdgcn_mfma_f32_16x16x32_bf16(af[i], bf[j], acc[i][j], 0, 0, 0);
        }
    }
    // epilogue: D frag layout row=lh*4+rr, col=l15
#pragma unroll
    for (int j = 0; j < 4; ++j) {
        int gcol = bcol + wn * 64 + j * 16 + l15;
        float bz = bias[gcol];
#pragma unroll
        for (int i = 0; i < 2; ++i) {
            int grow = brow + wm * 32 + i * 16 + lh * 4;
#pragma unroll
            for (int rr = 0; rr < 4; ++rr) {
                float v = acc[i][j][rr] + bz;
                if (OBF) Cb[(grow + rr) * DM + gcol] = f2bf(v);
                else     Cf[(grow + rr) * DM + gcol] = v;
            }
        }
    }
}

__global__ __launch_bounds__(256) void qkv_mfma_kernel(
        const u16* __restrict__ xb,
        const u16* __restrict__ WqT, const float* __restrict__ bq, u16* __restrict__ Qb,
        const u16* __restrict__ WkT, const float* __restrict__ bk, u16* __restrict__ Kb,
        const u16* __restrict__ WvT, const float* __restrict__ bv, u16* __restrict__ Vb) {
    const u16* Wt; const float* b; u16* C;
    if (blockIdx.z == 0)      { Wt = WqT; b = bq; C = Qb; }
    else if (blockIdx.z == 1) { Wt = WkT; b = bk; C = Kb; }
    else                      { Wt = WvT; b = bv; C = Vb; }
    gemm_mfma_body<true>(xb, Wt, b, C, nullptr);
}

__global__ __launch_bounds__(256) void oproj_mfma_kernel(
        const u16* __restrict__ Ob, const u16* __restrict__ WoT,
        const float* __restrict__ bo, float* __restrict__ out) {
    gemm_mfma_body<false>(Ob, WoT, bo, nullptr, out);
}

// ---------------------------------------------------------------------------
// Pre-pass 3: V bf16 [token][1024] -> VT bf16 [h][dh][token]
// ---------------------------------------------------------------------------
__global__ __launch_bounds__(256) void vT_kernel(const u16* __restrict__ Vb,
                                                 u16* __restrict__ VT) {
    const int j0 = blockIdx.x * 64, h = blockIdx.y;
    const int tid = threadIdx.x;
#pragma unroll
    for (int p = 0; p < 2; ++p) {
        int flat = tid + p * 256;
        int dh = flat >> 3, tc = flat & 7;
        u16x8 o;
#pragma unroll
        for (int t = 0; t < 8; ++t)
            o[t] = Vb[(j0 + tc * 8 + t) * DM + h * DH + dh];
        *(u16x8*)&VT[(h * DH + dh) * S_LEN + j0 + tc * 8] = o;
    }
}

// ---------------------------------------------------------------------------
// MFMA flash attention, NO-MAX softmax (scores bounded -> exp(s) safe in f32;
// softmax is shift-invariant so result matches reference).
// Per tile: QK MFMA -> exp -> lane-local row-sum accum -> P->LDS -> PV MFMA.
// ZERO cross-lane ops in the loop; one 4-round reduce at the end.
// K-frags prefetched one tile ahead; V-frags issued at loop top.
// ---------------------------------------------------------------------------
__global__ __launch_bounds__(256) void attn_mfma_kernel(const u16* __restrict__ Qb,
                                                        const u16* __restrict__ Kb,
                                                        const u16* __restrict__ VT,
                                                        u16* __restrict__ Ob) {
    __shared__ __align__(16) u16 Pl[4 * 16 * 72];
    const int tid = threadIdx.x;
    const int w = tid >> 6, l = tid & 63;
    const int l15 = l & 15, lh = l >> 4;
    const int i0 = blockIdx.x * 64, h = blockIdx.y;
    const int q0 = i0 + w * 16;
    u16* Pw = &Pl[w * 16 * 72];

    // Q A-frags (A[m=qrow][k=dh]): lane row l15, chunk ks*32 + lh*8
    bf16x8 qf[2];
    {
        int qr = q0 + l15;
        qf[0] = *(const bf16x8*)&Qb[qr * DM + h * DH + lh * 8];
        qf[1] = *(const bf16x8*)&Qb[qr * DM + h * DH + 32 + lh * 8];
    }

    f32x4 o[4];
    float ls[4] = {0.f, 0.f, 0.f, 0.f};
#pragma unroll
    for (int fc = 0; fc < 4; ++fc) o[fc] = (f32x4)0.f;

    // tile list: band tiles + global tile 0 (iff not already in band)
    int t_lo, t_hi;
    if (q0 == 0) { t_lo = 0; t_hi = S_LEN / 64 - 1; }
    else {
        int lo = q0 - WIN;      if (lo < 0) lo = 0;
        int hi = q0 + 15 + WIN; if (hi > S_LEN - 1) hi = S_LEN - 1;
        t_lo = lo >> 6; t_hi = hi >> 6;
    }
    const int nband = t_hi - t_lo + 1;
    const int nt = nband + (t_lo > 0 ? 1 : 0);

    // K-frag preload for tile 0
    bf16x8 kf[2][4];
    {
        const int j0 = t_lo << 6;
#pragma unroll
        for (int ks = 0; ks < 2; ++ks)
#pragma unroll
            for (int fc = 0; fc < 4; ++fc)
                kf[ks][fc] = *(const bf16x8*)&Kb[(j0 + fc * 16 + l15) * DM + h * DH + ks * 32 + lh * 8];
    }

    for (int it = 0; it < nt; ++it) {
        const int j0 = ((it < nband) ? (t_lo + it) : 0) << 6;

        // V-frags for current tile (consumed after exp -> latency covered)
        bf16x8 vf[2][4];
#pragma unroll
        for (int ks = 0; ks < 2; ++ks)
#pragma unroll
            for (int fc = 0; fc < 4; ++fc)
                vf[ks][fc] = *(const bf16x8*)&VT[(h * DH + fc * 16 + l15) * S_LEN + j0 + ks * 32 + lh * 8];

        // S = Q K^T
        f32x4 s[4];
#pragma unroll
        for (int fc = 0; fc < 4; ++fc) s[fc] = (f32x4)0.f;
#pragma unroll
        for (int ks = 0; ks < 2; ++ks)
#pragma unroll
            for (int fc = 0; fc < 4; ++fc)
                s[fc] = __builtin_amdgcn_mfma_f32_16x16x32_bf16(qf[ks], kf[ks][fc], s[fc], 0, 0, 0);

        // prefetch next tile's K-frags (last iter: reload current, unused)
        {
            const int itn = (it + 1 < nt) ? it + 1 : it;
            const int jn = ((itn < nband) ? (t_lo + itn) : 0) << 6;
            bf16x8 kn[2][4];
#pragma unroll
            for (int ks = 0; ks < 2; ++ks)
#pragma unroll
                for (int fc = 0; fc < 4; ++fc)
                    kn[ks][fc] = *(const bf16x8*)&Kb[(jn + fc * 16 + l15) * DM + h * DH + ks * 32 + lh * 8];

            // mask + exp (no max-sub) ; lane-local row-sum accumulate
#pragma unroll
            for (int fc = 0; fc < 4; ++fc)
#pragma unroll
                for (int rr = 0; rr < 4; ++rr) {
                    int r = q0 + lh * 4 + rr;
                    int c = j0 + fc * 16 + l15;
                    int d = r - c;
                    bool ok = (d <= WIN && -d <= WIN) || (r == 0) || (c == 0);
                    s[fc][rr] = ok ? __expf(s[fc][rr] * 0.125f) : 0.f;
                }
#pragma unroll
            for (int rr = 0; rr < 4; ++rr)
                ls[rr] += (s[0][rr] + s[1][rr]) + (s[2][rr] + s[3][rr]);

            // P -> wave-private LDS as bf16 [qrow16][kv64], pitch 72
#pragma unroll
            for (int fc = 0; fc < 4; ++fc)
#pragma unroll
                for (int rr = 0; rr < 4; ++rr)
                    Pw[(lh * 4 + rr) * 72 + fc * 16 + l15] = f2bf(s[fc][rr]);
            asm volatile("s_waitcnt lgkmcnt(0)" ::: "memory");

            // O += P V
#pragma unroll
            for (int ks = 0; ks < 2; ++ks) {
                bf16x8 pa = *(const bf16x8*)&Pw[l15 * 72 + ks * 32 + lh * 8];
#pragma unroll
                for (int fc = 0; fc < 4; ++fc)
                    o[fc] = __builtin_amdgcn_mfma_f32_16x16x32_bf16(pa, vf[ks][fc], o[fc], 0, 0, 0);
            }

            // rotate prefetched K into place
#pragma unroll
            for (int ks = 0; ks < 2; ++ks)
#pragma unroll
                for (int fc = 0; fc < 4; ++fc)
                    kf[ks][fc] = kn[ks][fc];
        }
    }

    // single cross-lane reduce of row sums (within each 16-lane lh group)
#pragma unroll
    for (int rr = 0; rr < 4; ++rr) {
#pragma unroll
        for (int mk = 1; mk < 16; mk <<= 1)
            ls[rr] += __shfl_xor(ls[rr], mk, 64);
    }

    // epilogue: /lsum, write bf16
#pragma unroll
    for (int rr = 0; rr < 4; ++rr) {
        float inv = 1.0f / ls[rr];
#pragma unroll
        for (int fc = 0; fc < 4; ++fc)
            Ob[(q0 + lh * 4 + rr) * DM + h * DH + fc * 16 + l15] = f2bf(o[fc][rr] * inv);
    }
}

// ---------------------------------------------------------------------------
extern "C" void kernel_launch(void* const* d_in, const int* in_sizes, int n_in,
                              void* d_out, int out_size, void* d_ws, size_t ws_size,
                              hipStream_t stream) {
    const float* x  = (const float*)d_in[0];
    const float* Wq = (const float*)d_in[1];
    const float* bq = (const float*)d_in[2];
    const float* Wk = (const float*)d_in[3];
    const float* bk = (const float*)d_in[4];
    const float* Wv = (const float*)d_in[5];
    const float* bv = (const float*)d_in[6];
    const float* Wo = (const float*)d_in[7];
    const float* bo = (const float*)d_in[8];
    float* out = (float*)d_out;

    char* W = (char*)d_ws;
    u16* xb  = (u16*)(W);                        // 4 MB  (reused as Ob after qkv)
    u16* WT  = (u16*)(W + ((size_t)4  << 20));   // 4 x 2 MB = 8 MB
    u16* Qb  = (u16*)(W + ((size_t)12 << 20));   // 4 MB
    u16* Kb  = (u16*)(W + ((size_t)16 << 20));   // 4 MB
    u16* Vb  = (u16*)(W + ((size_t)20 << 20));   // 4 MB
    u16* VT  = (u16*)(W + ((size_t)24 << 20));   // 4 MB   (total 28 MB)
    u16* Ob  = xb;                               // x dead after qkv
    const u16* WqT = WT;
    const u16* WkT = WT + (1u << 20);
    const u16* WvT = WT + (2u << 20);
    const u16* WoT = WT + (3u << 20);

    cvt_x_kernel <<<dim3(S_LEN * DM / (256 * 8)), 256, 0, stream>>>(x, xb);
    cvt_wT_kernel<<<dim3(16, 16, 4), 256, 0, stream>>>(Wq, Wk, Wv, Wo, WT);
    qkv_mfma_kernel<<<dim3(8, 32, 3), 256, 0, stream>>>(xb, WqT, bq, Qb,
                                                        WkT, bk, Kb, WvT, bv, Vb);
    vT_kernel<<<dim3(32, 16), 256, 0, stream>>>(Vb, VT);
    attn_mfma_kernel<<<dim3(32, 16), 256, 0, stream>>>(Qb, Kb, VT, Ob);
    oproj_mfma_kernel<<<dim3(8, 32), 256, 0, stream>>>(Ob, WoT, bo, out);
}